// Round 1
// baseline (3564.421 us; speedup 1.0000x reference)
//
#include <hip/hip_runtime.h>

// Problem constants (from reference)
constexpr int N_DST0 = 100000, N_DST1 = 20000, N_DST2 = 4096;
constexpr int E0 = 1000000, E1 = 300000, E2 = 61440;

// ---------------------------------------------------------------------------
// Scatter-add: agg[dst[e]] += h[src[e]] (vectorized float4 per thread-item),
// deg[dst[e]] += 1. D4 = row length / 4 (template so idx/D4 is a shift).
// ---------------------------------------------------------------------------
template <int D4>
__global__ void scatter_add_kernel(const float* __restrict__ h,
                                   const int* __restrict__ src,
                                   const int* __restrict__ dst,
                                   float* __restrict__ agg,
                                   float* __restrict__ deg, int E) {
  int total = E * D4;
  int stride = gridDim.x * blockDim.x;
  for (int idx = blockIdx.x * blockDim.x + threadIdx.x; idx < total; idx += stride) {
    int e = idx / D4;
    int c = idx - e * D4;
    int s = src[e];
    int d = dst[e];
    float4 v = reinterpret_cast<const float4*>(h)[(long long)s * D4 + c];
    float* a = agg + ((long long)d * D4 + c) * 4;
    atomicAdd(a + 0, v.x);
    atomicAdd(a + 1, v.y);
    atomicAdd(a + 2, v.z);
    atomicAdd(a + 3, v.w);
    if (c == 0) atomicAdd(deg + d, 1.0f);
  }
}

// agg[r][:] *= 1/max(deg[r],1)
template <int D4>
__global__ void scale_rows_kernel(float* __restrict__ agg,
                                  const float* __restrict__ deg, int M) {
  int total = M * D4;
  int stride = gridDim.x * blockDim.x;
  for (int idx = blockIdx.x * blockDim.x + threadIdx.x; idx < total; idx += stride) {
    int r = idx / D4;
    float s = 1.0f / fmaxf(deg[r], 1.0f);
    float4* p = reinterpret_cast<float4*>(agg) + idx;
    float4 v = *p;
    v.x *= s; v.y *= s; v.z *= s; v.w *= s;
    *p = v;
  }
}

// ---------------------------------------------------------------------------
// Fused GEMM: C[M,N] = Aself[M,Ks] @ Wself[Ks,N] + Aneigh[M,Kn] @ Wneigh[Kn,N]
//             + bias, optional ReLU. Aneigh is pre-scaled by 1/deg.
// 64x64 tile, 256 threads, 4x4 micro-tile/thread, TK=16 k-major LDS staging.
// Requires Ks, Kn multiples of TK (128/256 here).
// ---------------------------------------------------------------------------
__global__ __launch_bounds__(256)
void gemm_fused(const float* __restrict__ Aself, int Ks,
                const float* __restrict__ Wself,
                const float* __restrict__ Aneigh, int Kn,
                const float* __restrict__ Wneigh,
                const float* __restrict__ bias, float* __restrict__ C,
                int M, int N, int do_relu) {
  constexpr int TM = 64, TN = 64, TK = 16, APAD = 76;  // 76*4B %16==0, breaks bank alias
  __shared__ __align__(16) float As[TK][APAD];  // k-major: As[k][m]
  __shared__ __align__(16) float Bs[TK][TN];    // Bs[k][n]

  const int tid = threadIdx.x;
  const int m0 = blockIdx.x * TM;
  const int n0 = blockIdx.y * TN;
  const int tx = tid & 15;       // col group
  const int ty = tid >> 4;       // row group
  const int am = tid >> 2;       // A staging: row within tile
  const int akq = (tid & 3) * 4; // A staging: k quad
  const int wj = tid & 63;       // W staging: col within tile
  const int wk0 = (tid >> 6) * 4;

  float acc[4][4] = {};
  const int ktot = Ks + Kn;

  for (int k0 = 0; k0 < ktot; k0 += TK) {
    // --- stage A (64 rows x 16 k), one float4 per thread ---
    int gm = m0 + am;
    float4 av = make_float4(0.f, 0.f, 0.f, 0.f);
    if (gm < M) {
      if (k0 < Ks)
        av = *reinterpret_cast<const float4*>(Aself + (long long)gm * Ks + k0 + akq);
      else
        av = *reinterpret_cast<const float4*>(Aneigh + (long long)gm * Kn + (k0 - Ks) + akq);
    }
    As[akq + 0][am] = av.x;
    As[akq + 1][am] = av.y;
    As[akq + 2][am] = av.z;
    As[akq + 3][am] = av.w;
    // --- stage W (16 k x 64 cols), 4 scalars per thread ---
#pragma unroll
    for (int i = 0; i < 4; ++i) {
      int k = k0 + wk0 + i;
      int gj = n0 + wj;
      float wv = 0.f;
      if (gj < N) {
        if (k < Ks) wv = Wself[(long long)k * N + gj];
        else        wv = Wneigh[(long long)(k - Ks) * N + gj];
      }
      Bs[wk0 + i][wj] = wv;
    }
    __syncthreads();
#pragma unroll
    for (int kk = 0; kk < TK; ++kk) {
      float4 avr = *reinterpret_cast<const float4*>(&As[kk][ty * 4]);
      float4 bvr = *reinterpret_cast<const float4*>(&Bs[kk][tx * 4]);
      float ar[4] = {avr.x, avr.y, avr.z, avr.w};
      float br[4] = {bvr.x, bvr.y, bvr.z, bvr.w};
#pragma unroll
      for (int i = 0; i < 4; ++i)
#pragma unroll
        for (int j = 0; j < 4; ++j) acc[i][j] += ar[i] * br[j];
    }
    __syncthreads();
  }

  // --- epilogue: bias (+ReLU), store ---
  const int c0 = n0 + tx * 4;
#pragma unroll
  for (int i = 0; i < 4; ++i) {
    int r = m0 + ty * 4 + i;
    if (r >= M) continue;
    if (((N & 3) == 0) && (c0 + 3 < N)) {
      float4 o;
      o.x = acc[i][0] + bias[c0 + 0];
      o.y = acc[i][1] + bias[c0 + 1];
      o.z = acc[i][2] + bias[c0 + 2];
      o.w = acc[i][3] + bias[c0 + 3];
      if (do_relu) {
        o.x = fmaxf(o.x, 0.f); o.y = fmaxf(o.y, 0.f);
        o.z = fmaxf(o.z, 0.f); o.w = fmaxf(o.w, 0.f);
      }
      *reinterpret_cast<float4*>(C + (long long)r * N + c0) = o;
    } else {
#pragma unroll
      for (int j = 0; j < 4; ++j) {
        int c = c0 + j;
        if (c < N) {
          float v = acc[i][j] + bias[c];
          if (do_relu) v = fmaxf(v, 0.f);
          C[(long long)r * N + c] = v;
        }
      }
    }
  }
}

extern "C" void kernel_launch(void* const* d_in, const int* in_sizes, int n_in,
                              void* d_out, int out_size, void* d_ws, size_t ws_size,
                              hipStream_t stream) {
  const float* x   = (const float*)d_in[0];
  const int* src0  = (const int*)d_in[1];
  const int* dst0  = (const int*)d_in[2];
  const int* src1  = (const int*)d_in[3];
  const int* dst1  = (const int*)d_in[4];
  const int* src2  = (const int*)d_in[5];
  const int* dst2  = (const int*)d_in[6];
  const float* Ws0 = (const float*)d_in[7];
  const float* Wn0 = (const float*)d_in[8];
  const float* b0  = (const float*)d_in[9];
  const float* Ws1 = (const float*)d_in[10];
  const float* Wn1 = (const float*)d_in[11];
  const float* b1  = (const float*)d_in[12];
  const float* Ws2 = (const float*)d_in[13];
  const float* Wn2 = (const float*)d_in[14];
  const float* b2  = (const float*)d_in[15];
  float* out = (float*)d_out;

  // Workspace layout (floats):
  //   h0:   25,600,000           (100000 x 256)
  //   B:    12,800,000           agg0 (100000x128); later agg1(5.12M)+h1(5.12M)+agg2(1.05M)
  //   degs:    124,096           deg0(100000) deg1(20000) deg2(4096)
  float* h0   = (float*)d_ws;
  float* B    = h0 + 25600000LL;
  float* degs = B + 12800000LL;
  float* agg0 = B;
  float* agg1 = B;
  float* h1   = B + 5120000LL;
  float* agg2 = B + 10240000LL;
  float* deg0 = degs;
  float* deg1 = degs + 100000;
  float* deg2 = degs + 120000;

  // ---- layer 0: x(300000,128) -> h0(100000,256) ----
  hipMemsetAsync(agg0, 0, 12800000LL * 4, stream);
  hipMemsetAsync(degs, 0, 124096LL * 4, stream);
  scatter_add_kernel<32><<<2048, 256, 0, stream>>>(x, src0, dst0, agg0, deg0, E0);
  scale_rows_kernel<32><<<2048, 256, 0, stream>>>(agg0, deg0, N_DST0);
  gemm_fused<<<dim3((N_DST0 + 63) / 64, 4), 256, 0, stream>>>(
      x, 128, Ws0, agg0, 128, Wn0, b0, h0, N_DST0, 256, 1);

  // ---- layer 1: h0(100000,256) -> h1(20000,256) ----
  hipMemsetAsync(agg1, 0, 5120000LL * 4, stream);
  scatter_add_kernel<64><<<2048, 256, 0, stream>>>(h0, src1, dst1, agg1, deg1, E1);
  scale_rows_kernel<64><<<2048, 256, 0, stream>>>(agg1, deg1, N_DST1);
  gemm_fused<<<dim3((N_DST1 + 63) / 64, 4), 256, 0, stream>>>(
      h0, 256, Ws1, agg1, 256, Wn1, b1, h1, N_DST1, 256, 1);

  // ---- layer 2: h1(20000,256) -> out(4096,47) ----
  hipMemsetAsync(agg2, 0, 1048576LL * 4, stream);
  scatter_add_kernel<64><<<2048, 256, 0, stream>>>(h1, src2, dst2, agg2, deg2, E2);
  scale_rows_kernel<64><<<2048, 256, 0, stream>>>(agg2, deg2, N_DST2);
  gemm_fused<<<dim3((N_DST2 + 63) / 64, 1), 256, 0, stream>>>(
      h1, 256, Ws2, agg2, 256, Wn2, b2, out, N_DST2, 47, 0);
}

// Round 3
// 912.764 us; speedup vs baseline: 3.9051x; 3.9051x over previous
//
#include <hip/hip_runtime.h>

// Problem constants (from reference)
constexpr int N_DST0 = 100000, N_DST1 = 20000, N_DST2 = 4096;
constexpr int E0 = 1000000, E1 = 300000, E2 = 61440;

// ---------------------------------------------------------------------------
// CSR build: count -> exclusive scan (3-kernel, <=256*1024 elems) -> place
// ---------------------------------------------------------------------------
__global__ void count_kernel(const int* __restrict__ dst, int* __restrict__ cnt, int E) {
  int stride = gridDim.x * blockDim.x;
  for (int i = blockIdx.x * blockDim.x + threadIdx.x; i < E; i += stride)
    atomicAdd(&cnt[dst[i]], 1);
}

// exclusive scan of in[0..n) into out[0..n), 1024 elems per 256-thread block
__global__ __launch_bounds__(256)
void scanA(const int* __restrict__ in, int* __restrict__ out,
           int* __restrict__ bsums, int n) {
  __shared__ int lds[256];
  const int t = threadIdx.x;
  const int idx = blockIdx.x * 1024 + t * 4;
  int v[4];
#pragma unroll
  for (int j = 0; j < 4; ++j) v[j] = (idx + j < n) ? in[idx + j] : 0;
  int s = v[0] + v[1] + v[2] + v[3];
  lds[t] = s;
  __syncthreads();
  for (int off = 1; off < 256; off <<= 1) {
    int x = (t >= off) ? lds[t - off] : 0;
    __syncthreads();
    lds[t] += x;
    __syncthreads();
  }
  if (t == 255) bsums[blockIdx.x] = lds[255];
  int run = lds[t] - s;  // exclusive prefix of this thread's chunk
#pragma unroll
  for (int j = 0; j < 4; ++j) {
    if (idx + j < n) out[idx + j] = run;
    run += v[j];
  }
}

__global__ __launch_bounds__(256)
void scanB(int* __restrict__ bsums, int nb) {
  __shared__ int lds[256];
  const int t = threadIdx.x;
  int s = (t < nb) ? bsums[t] : 0;
  lds[t] = s;
  __syncthreads();
  for (int off = 1; off < 256; off <<= 1) {
    int x = (t >= off) ? lds[t - off] : 0;
    __syncthreads();
    lds[t] += x;
    __syncthreads();
  }
  if (t < nb) bsums[t] = lds[t] - s;  // exclusive
}

__global__ __launch_bounds__(256)
void scanC(int* __restrict__ out, const int* __restrict__ bsums, int n) {
  const int add = bsums[blockIdx.x];
  const int idx = blockIdx.x * 1024 + threadIdx.x * 4;
#pragma unroll
  for (int j = 0; j < 4; ++j)
    if (idx + j < n) out[idx + j] += add;
}

__global__ void place_kernel(const int* __restrict__ src, const int* __restrict__ dst,
                             int* __restrict__ cursor, int* __restrict__ eidx, int E) {
  int stride = gridDim.x * blockDim.x;
  for (int i = blockIdx.x * blockDim.x + threadIdx.x; i < E; i += stride) {
    int pos = atomicAdd(&cursor[dst[i]], 1);
    eidx[pos] = src[i];
  }
}

// ---------------------------------------------------------------------------
// Gather-mean: one block per dst row, one thread per feature column.
// out[d] = (1/max(deg,1)) * sum_{e in row d} h[eidx[e]]
// ---------------------------------------------------------------------------
template <int D>
__global__ __launch_bounds__(D)
void gather_mean_kernel(const float* __restrict__ h,
                        const int* __restrict__ rowptr,
                        const int* __restrict__ eidx,
                        float* __restrict__ out) {
  const int d = blockIdx.x;
  const int t = threadIdx.x;
  const int beg = rowptr[d], end = rowptr[d + 1];
  float acc = 0.f;
  int e = beg;
  for (; e + 4 <= end; e += 4) {
    int s0 = eidx[e + 0], s1 = eidx[e + 1], s2 = eidx[e + 2], s3 = eidx[e + 3];
    acc += h[(long long)s0 * D + t];
    acc += h[(long long)s1 * D + t];
    acc += h[(long long)s2 * D + t];
    acc += h[(long long)s3 * D + t];
  }
  for (; e < end; ++e) acc += h[(long long)eidx[e] * D + t];
  const float inv = 1.f / fmaxf((float)(end - beg), 1.f);
  out[(long long)d * D + t] = acc * inv;
}

// ---------------------------------------------------------------------------
// Fused GEMM: C[M,N] = Aself[M,Ks]@Wself + Aneigh[M,Kn]@Wneigh + bias (+ReLU)
// 64x64 tile, 256 threads, 4x4 micro-tile, TK=16 k-major LDS staging.
// ---------------------------------------------------------------------------
__global__ __launch_bounds__(256)
void gemm_fused(const float* __restrict__ Aself, int Ks,
                const float* __restrict__ Wself,
                const float* __restrict__ Aneigh, int Kn,
                const float* __restrict__ Wneigh,
                const float* __restrict__ bias, float* __restrict__ C,
                int M, int N, int do_relu) {
  constexpr int TM = 64, TN = 64, TK = 16, APAD = 76;
  __shared__ __align__(16) float As[TK][APAD];  // k-major: As[k][m]
  __shared__ __align__(16) float Bs[TK][TN];    // Bs[k][n]

  const int tid = threadIdx.x;
  const int m0 = blockIdx.x * TM;
  const int n0 = blockIdx.y * TN;
  const int tx = tid & 15;
  const int ty = tid >> 4;
  const int am = tid >> 2;
  const int akq = (tid & 3) * 4;
  const int wj = tid & 63;
  const int wk0 = (tid >> 6) * 4;

  float acc[4][4] = {};
  const int ktot = Ks + Kn;

  for (int k0 = 0; k0 < ktot; k0 += TK) {
    int gm = m0 + am;
    float4 av = make_float4(0.f, 0.f, 0.f, 0.f);
    if (gm < M) {
      if (k0 < Ks)
        av = *reinterpret_cast<const float4*>(Aself + (long long)gm * Ks + k0 + akq);
      else
        av = *reinterpret_cast<const float4*>(Aneigh + (long long)gm * Kn + (k0 - Ks) + akq);
    }
    As[akq + 0][am] = av.x;
    As[akq + 1][am] = av.y;
    As[akq + 2][am] = av.z;
    As[akq + 3][am] = av.w;
#pragma unroll
    for (int i = 0; i < 4; ++i) {
      int k = k0 + wk0 + i;
      int gj = n0 + wj;
      float wv = 0.f;
      if (gj < N) {
        if (k < Ks) wv = Wself[(long long)k * N + gj];
        else        wv = Wneigh[(long long)(k - Ks) * N + gj];
      }
      Bs[wk0 + i][wj] = wv;
    }
    __syncthreads();
#pragma unroll
    for (int kk = 0; kk < TK; ++kk) {
      float4 avr = *reinterpret_cast<const float4*>(&As[kk][ty * 4]);
      float4 bvr = *reinterpret_cast<const float4*>(&Bs[kk][tx * 4]);
      float ar[4] = {avr.x, avr.y, avr.z, avr.w};
      float br[4] = {bvr.x, bvr.y, bvr.z, bvr.w};
#pragma unroll
      for (int i = 0; i < 4; ++i)
#pragma unroll
        for (int j = 0; j < 4; ++j) acc[i][j] += ar[i] * br[j];
    }
    __syncthreads();
  }

  const int c0 = n0 + tx * 4;
#pragma unroll
  for (int i = 0; i < 4; ++i) {
    int r = m0 + ty * 4 + i;
    if (r >= M) continue;
    if (((N & 3) == 0) && (c0 + 3 < N)) {
      float4 o;
      o.x = acc[i][0] + bias[c0 + 0];
      o.y = acc[i][1] + bias[c0 + 1];
      o.z = acc[i][2] + bias[c0 + 2];
      o.w = acc[i][3] + bias[c0 + 3];
      if (do_relu) {
        o.x = fmaxf(o.x, 0.f); o.y = fmaxf(o.y, 0.f);
        o.z = fmaxf(o.z, 0.f); o.w = fmaxf(o.w, 0.f);
      }
      *reinterpret_cast<float4*>(C + (long long)r * N + c0) = o;
    } else {
#pragma unroll
      for (int j = 0; j < 4; ++j) {
        int c = c0 + j;
        if (c < N) {
          float v = acc[i][j] + bias[c];
          if (do_relu) v = fmaxf(v, 0.f);
          C[(long long)r * N + c] = v;
        }
      }
    }
  }
}

// ---------------------------------------------------------------------------
static void build_csr(const int* src, const int* dst, int E, int n,
                      int* rowptr, int* cursor, int* bsums, int* eidx,
                      hipStream_t stream) {
  const int n1 = n + 1;
  hipMemsetAsync(cursor, 0, (size_t)n1 * 4, stream);
  count_kernel<<<2048, 256, 0, stream>>>(dst, cursor, E);
  const int nb = (n1 + 1023) / 1024;
  scanA<<<nb, 256, 0, stream>>>(cursor, rowptr, bsums, n1);
  scanB<<<1, 256, 0, stream>>>(bsums, nb);
  scanC<<<nb, 256, 0, stream>>>(rowptr, bsums, n1);
  hipMemcpyAsync(cursor, rowptr, (size_t)n1 * 4, hipMemcpyDeviceToDevice, stream);
  place_kernel<<<2048, 256, 0, stream>>>(src, dst, cursor, eidx, E);
}

extern "C" void kernel_launch(void* const* d_in, const int* in_sizes, int n_in,
                              void* d_out, int out_size, void* d_ws, size_t ws_size,
                              hipStream_t stream) {
  const float* x   = (const float*)d_in[0];
  const int* src0  = (const int*)d_in[1];
  const int* dst0  = (const int*)d_in[2];
  const int* src1  = (const int*)d_in[3];
  const int* dst1  = (const int*)d_in[4];
  const int* src2  = (const int*)d_in[5];
  const int* dst2  = (const int*)d_in[6];
  const float* Ws0 = (const float*)d_in[7];
  const float* Wn0 = (const float*)d_in[8];
  const float* b0  = (const float*)d_in[9];
  const float* Ws1 = (const float*)d_in[10];
  const float* Wn1 = (const float*)d_in[11];
  const float* b1  = (const float*)d_in[12];
  const float* Ws2 = (const float*)d_in[13];
  const float* Wn2 = (const float*)d_in[14];
  const float* b2  = (const float*)d_in[15];
  float* out = (float*)d_out;

  // Workspace (floats/ints):
  //   h0:     25,600,000 f   (100000 x 256)
  //   B:      12,800,000 f   agg0(12.8M); later agg1(5.12M)+h1(5.12M)+agg2(1.05M)
  //   eidx:    1,000,000 i
  //   rowptr:    100,032 i   cursor: 100,032 i   bsums: 256 i
  float* h0   = (float*)d_ws;
  float* B    = h0 + 25600000LL;
  int* eidx   = (int*)(B + 12800000LL);
  int* rowptr = eidx + 1000000;
  int* cursor = rowptr + 100032;
  int* bsums  = cursor + 100032;

  float* agg0 = B;
  float* agg1 = B;
  float* h1   = B + 5120000LL;
  float* agg2 = B + 10240000LL;

  // ---- layer 0: x(300000,128) -> h0(100000,256) ----
  build_csr(src0, dst0, E0, N_DST0, rowptr, cursor, bsums, eidx, stream);
  gather_mean_kernel<128><<<N_DST0, 128, 0, stream>>>(x, rowptr, eidx, agg0);
  gemm_fused<<<dim3((N_DST0 + 63) / 64, 4), 256, 0, stream>>>(
      x, 128, Ws0, agg0, 128, Wn0, b0, h0, N_DST0, 256, 1);

  // ---- layer 1: h0(100000,256) -> h1(20000,256) ----
  build_csr(src1, dst1, E1, N_DST1, rowptr, cursor, bsums, eidx, stream);
  gather_mean_kernel<256><<<N_DST1, 256, 0, stream>>>(h0, rowptr, eidx, agg1);
  gemm_fused<<<dim3((N_DST1 + 63) / 64, 4), 256, 0, stream>>>(
      h0, 256, Ws1, agg1, 256, Wn1, b1, h1, N_DST1, 256, 1);

  // ---- layer 2: h1(20000,256) -> out(4096,47) ----
  build_csr(src2, dst2, E2, N_DST2, rowptr, cursor, bsums, eidx, stream);
  gather_mean_kernel<256><<<N_DST2, 256, 0, stream>>>(h1, rowptr, eidx, agg2);
  gemm_fused<<<dim3((N_DST2 + 63) / 64, 1), 256, 0, stream>>>(
      h1, 256, Ws2, agg2, 256, Wn2, b2, out, N_DST2, 47, 0);
}

// Round 4
// 603.659 us; speedup vs baseline: 5.9047x; 1.5121x over previous
//
#include <hip/hip_runtime.h>

typedef __bf16 bf16x8 __attribute__((ext_vector_type(8)));
typedef float f32x4 __attribute__((ext_vector_type(4)));

constexpr int N_DST0 = 100000, N_DST1 = 20000, N_DST2 = 4096;
constexpr int E0 = 1000000, E1 = 300000, E2 = 61440;

// ---- bf16 helpers (no hip_bf16.h dependency; RNE rounding) ----
__device__ __forceinline__ unsigned short f2b(float f) {
  unsigned u = __builtin_bit_cast(unsigned, f);
  u += 0x7FFFu + ((u >> 16) & 1u);
  return (unsigned short)(u >> 16);
}
__device__ __forceinline__ float b2f_lo(unsigned u) {
  return __builtin_bit_cast(float, u << 16);
}
__device__ __forceinline__ float b2f_hi(unsigned u) {
  return __builtin_bit_cast(float, u & 0xFFFF0000u);
}

// ---------------------------------------------------------------------------
// fp32 -> bf16 bulk convert (float4 in, ushort4 out)
// ---------------------------------------------------------------------------
__global__ __launch_bounds__(256)
void f2b_kernel(const float4* __restrict__ in, ushort4* __restrict__ out, int n4) {
  int stride = gridDim.x * blockDim.x;
  for (int i = blockIdx.x * blockDim.x + threadIdx.x; i < n4; i += stride) {
    float4 v = in[i];
    ushort4 o;
    o.x = f2b(v.x); o.y = f2b(v.y); o.z = f2b(v.z); o.w = f2b(v.w);
    out[i] = o;
  }
}

// ---------------------------------------------------------------------------
// Weight repack: W = [Ws ; Wn] (concat along K, row-major [K,N]) into
// fragment-ordered bf16: out[((nt*NKT + kt)*64 + lane)*8 + j]
//   = W[kt*32 + (lane>>4)*8 + j][nt*16 + (lane&15)], zero-pad n >= N.
// Same k-mapping as the A-frag loader => correct for any HW k-permutation.
// ---------------------------------------------------------------------------
__global__ __launch_bounds__(256)
void pack_w_kernel(const float* __restrict__ Ws, const float* __restrict__ Wn,
                   unsigned short* __restrict__ out, int KS, int KN, int N, int NP) {
  int NKT = (KS + KN) >> 5;
  int total = (NP >> 4) * NKT * 512;
  int stride = gridDim.x * blockDim.x;
  for (int t = blockIdx.x * blockDim.x + threadIdx.x; t < total; t += stride) {
    int j = t & 7, lane = (t >> 3) & 63;
    int kt = (t >> 9) % NKT, nt = t / (NKT << 9);
    int k = kt * 32 + (lane >> 4) * 8 + j;
    int n = nt * 16 + (lane & 15);
    float v = 0.f;
    if (n < N) v = (k < KS) ? Ws[k * N + n] : Wn[(k - KS) * N + n];
    out[t] = f2b(v);
  }
}

// ---------------------------------------------------------------------------
// CSR build: count -> in-place exclusive scan -> place.
// After place_kernel, cursor[d] == row_end(d); row_beg(d) = d ? cursor[d-1] : 0
// ---------------------------------------------------------------------------
__global__ void count_kernel(const int* __restrict__ dst, int* __restrict__ cnt, int E) {
  int stride = gridDim.x * blockDim.x;
  for (int i = blockIdx.x * blockDim.x + threadIdx.x; i < E; i += stride)
    atomicAdd(&cnt[dst[i]], 1);
}

__global__ __launch_bounds__(256)
void scanA(const int* __restrict__ in, int* __restrict__ out,
           int* __restrict__ bsums, int n) {
  __shared__ int lds[256];
  const int t = threadIdx.x;
  const int idx = blockIdx.x * 1024 + t * 4;
  int v[4];
#pragma unroll
  for (int j = 0; j < 4; ++j) v[j] = (idx + j < n) ? in[idx + j] : 0;
  int s = v[0] + v[1] + v[2] + v[3];
  lds[t] = s;
  __syncthreads();
  for (int off = 1; off < 256; off <<= 1) {
    int x = (t >= off) ? lds[t - off] : 0;
    __syncthreads();
    lds[t] += x;
    __syncthreads();
  }
  if (t == 255) bsums[blockIdx.x] = lds[255];
  int run = lds[t] - s;
#pragma unroll
  for (int j = 0; j < 4; ++j) {
    if (idx + j < n) out[idx + j] = run;
    run += v[j];
  }
}

__global__ __launch_bounds__(256)
void scanB(int* __restrict__ bsums, int nb) {
  __shared__ int lds[256];
  const int t = threadIdx.x;
  int s = (t < nb) ? bsums[t] : 0;
  lds[t] = s;
  __syncthreads();
  for (int off = 1; off < 256; off <<= 1) {
    int x = (t >= off) ? lds[t - off] : 0;
    __syncthreads();
    lds[t] += x;
    __syncthreads();
  }
  if (t < nb) bsums[t] = lds[t] - s;
}

__global__ __launch_bounds__(256)
void scanC(int* __restrict__ out, const int* __restrict__ bsums, int n) {
  const int add = bsums[blockIdx.x];
  const int idx = blockIdx.x * 1024 + threadIdx.x * 4;
#pragma unroll
  for (int j = 0; j < 4; ++j)
    if (idx + j < n) out[idx + j] += add;
}

__global__ void place_kernel(const int* __restrict__ src, const int* __restrict__ dst,
                             int* __restrict__ cursor, int* __restrict__ eidx, int E) {
  int stride = gridDim.x * blockDim.x;
  for (int i = blockIdx.x * blockDim.x + threadIdx.x; i < E; i += stride) {
    int pos = atomicAdd(&cursor[dst[i]], 1);
    eidx[pos] = src[i];
  }
}

// ---------------------------------------------------------------------------
// Gather-mean over bf16 rows: one wave per dst row, lane covers D/64 columns.
// fp32 accumulate, bf16 output.
// ---------------------------------------------------------------------------
template <int D>
__global__ __launch_bounds__(256)
void gather_mean_bf16(const unsigned short* __restrict__ h,
                      const int* __restrict__ cursor,
                      const int* __restrict__ eidx,
                      unsigned short* __restrict__ out, int ndst) {
  constexpr int VEC = D / 64;   // 2 (D=128) or 4 (D=256)
  constexpr int NU = VEC / 2;   // uints per lane per row
  const int w = blockIdx.x * 4 + (threadIdx.x >> 6);
  if (w >= ndst) return;
  const int lane = threadIdx.x & 63;
  const int beg = (w == 0) ? 0 : cursor[w - 1];
  const int end = cursor[w];
  float acc[VEC] = {};
  const unsigned short* hp = h + lane * VEC;
  int e = beg;
  for (; e + 4 <= end; e += 4) {
    const unsigned int* p0 = (const unsigned int*)(hp + (long long)eidx[e] * D);
    const unsigned int* p1 = (const unsigned int*)(hp + (long long)eidx[e + 1] * D);
    const unsigned int* p2 = (const unsigned int*)(hp + (long long)eidx[e + 2] * D);
    const unsigned int* p3 = (const unsigned int*)(hp + (long long)eidx[e + 3] * D);
    unsigned int u[4][NU];
#pragma unroll
    for (int v = 0; v < NU; ++v) {
      u[0][v] = p0[v]; u[1][v] = p1[v]; u[2][v] = p2[v]; u[3][v] = p3[v];
    }
#pragma unroll
    for (int q = 0; q < 4; ++q)
#pragma unroll
      for (int v = 0; v < NU; ++v) {
        acc[2 * v]     += b2f_lo(u[q][v]);
        acc[2 * v + 1] += b2f_hi(u[q][v]);
      }
  }
  for (; e < end; ++e) {
    const unsigned int* p = (const unsigned int*)(hp + (long long)eidx[e] * D);
#pragma unroll
    for (int v = 0; v < NU; ++v) {
      unsigned int x = p[v];
      acc[2 * v]     += b2f_lo(x);
      acc[2 * v + 1] += b2f_hi(x);
    }
  }
  const float inv = 1.f / fmaxf((float)(end - beg), 1.f);
  unsigned int* po = (unsigned int*)(out + (long long)w * D + lane * VEC);
#pragma unroll
  for (int v = 0; v < NU; ++v)
    po[v] = (unsigned int)f2b(acc[2 * v] * inv) |
            ((unsigned int)f2b(acc[2 * v + 1] * inv) << 16);
}

// ---------------------------------------------------------------------------
// MFMA GEMM: C[M,NOUT] = [As|An][M,KS+KN] @ Wp + bias (+ReLU).
// One wave per 16-row strip: A-frags held in registers for the whole K,
// packed W streamed from L2, 2 independent acc chains for MFMA ILP.
// A-frag: lane holds A[m0+(lane&15)][kt*32 + (lane>>4)*8 + j]  (same k-map as pack)
// C/D:    row = m0 + (lane>>4)*4 + reg, col = nt*16 + (lane&15)   [m89-verified]
// ---------------------------------------------------------------------------
template <int KS, int KN, int NP, int NOUT, bool RELU, bool OUT_BF16>
__global__ __launch_bounds__(256)
void gemm_mfma(const unsigned short* __restrict__ As,
               const unsigned short* __restrict__ An,
               const unsigned short* __restrict__ Wp,
               const float* __restrict__ bias, void* __restrict__ Cout, int M) {
  constexpr int NK = (KS + KN) / 32, NT = NP / 16;
  const int wave = blockIdx.x * 4 + (threadIdx.x >> 6);
  const int m0 = wave * 16;
  if (m0 >= M) return;
  const int lane = threadIdx.x & 63;
  const int g = lane >> 4, mi = lane & 15;
  const long long row = m0 + mi;

  bf16x8 a[NK];
#pragma unroll
  for (int kt = 0; kt < NK; ++kt) {
    const int k = kt * 32 + g * 8;
    const unsigned short* p = (kt * 32 < KS) ? (As + row * KS + k)
                                             : (An + row * KN + (k - KS));
    a[kt] = *reinterpret_cast<const bf16x8*>(p);
  }
  const bf16x8* wp = reinterpret_cast<const bf16x8*>(Wp);

  auto emit = [&](int nt, const f32x4& acc) {
    const int col = nt * 16 + mi;
    if (col < NOUT) {
      const float bv = bias[col];
#pragma unroll
      for (int j = 0; j < 4; ++j) {
        const long long r = m0 + g * 4 + j;
        float v = acc[j] + bv;
        if (RELU) v = fmaxf(v, 0.f);
        if (OUT_BF16) ((unsigned short*)Cout)[r * NOUT + col] = f2b(v);
        else          ((float*)Cout)[r * NOUT + col] = v;
      }
    }
  };

#pragma unroll 1
  for (int nt = 0; nt + 2 <= NT; nt += 2) {
    f32x4 acc0 = {0.f, 0.f, 0.f, 0.f}, acc1 = {0.f, 0.f, 0.f, 0.f};
#pragma unroll
    for (int kt = 0; kt < NK; ++kt) {
      bf16x8 b0 = wp[(nt * NK + kt) * 64 + lane];
      bf16x8 b1 = wp[((nt + 1) * NK + kt) * 64 + lane];
      acc0 = __builtin_amdgcn_mfma_f32_16x16x32_bf16(a[kt], b0, acc0, 0, 0, 0);
      acc1 = __builtin_amdgcn_mfma_f32_16x16x32_bf16(a[kt], b1, acc1, 0, 0, 0);
    }
    emit(nt, acc0);
    emit(nt + 1, acc1);
  }
  if (NT & 1) {
    f32x4 acc = {0.f, 0.f, 0.f, 0.f};
#pragma unroll
    for (int kt = 0; kt < NK; ++kt)
      acc = __builtin_amdgcn_mfma_f32_16x16x32_bf16(
          a[kt], wp[((NT - 1) * NK + kt) * 64 + lane], acc, 0, 0, 0);
    emit(NT - 1, acc);
  }
}

// ---------------------------------------------------------------------------
static void build_csr(const int* src, const int* dst, int E, int n,
                      int* cursor, int* bsums, int* eidx, hipStream_t stream) {
  hipMemsetAsync(cursor, 0, (size_t)n * 4, stream);
  count_kernel<<<2048, 256, 0, stream>>>(dst, cursor, E);
  const int nb = (n + 1023) / 1024;
  scanA<<<nb, 256, 0, stream>>>(cursor, cursor, bsums, n);   // in-place safe
  scanB<<<1, 256, 0, stream>>>(bsums, nb);
  scanC<<<nb, 256, 0, stream>>>(cursor, bsums, n);
  place_kernel<<<2048, 256, 0, stream>>>(src, dst, cursor, eidx, E);
}

extern "C" void kernel_launch(void* const* d_in, const int* in_sizes, int n_in,
                              void* d_out, int out_size, void* d_ws, size_t ws_size,
                              hipStream_t stream) {
  const float* x   = (const float*)d_in[0];
  const int* src0  = (const int*)d_in[1];
  const int* dst0  = (const int*)d_in[2];
  const int* src1  = (const int*)d_in[3];
  const int* dst1  = (const int*)d_in[4];
  const int* src2  = (const int*)d_in[5];
  const int* dst2  = (const int*)d_in[6];
  const float* Ws0 = (const float*)d_in[7];
  const float* Wn0 = (const float*)d_in[8];
  const float* b0  = (const float*)d_in[9];
  const float* Ws1 = (const float*)d_in[10];
  const float* Wn1 = (const float*)d_in[11];
  const float* b1  = (const float*)d_in[12];
  const float* Ws2 = (const float*)d_in[13];
  const float* Wn2 = (const float*)d_in[14];
  const float* b2  = (const float*)d_in[15];
  float* out = (float*)d_out;

  // Workspace layout (bytes, all 16B-aligned):
  //   xb   @0           76,800,000  (300000x128 bf16; h1b reuses front after gemm0)
  //   h0b  @76,800,000  51,200,000  (100000x256 bf16)
  //   R    @128,000,000 25,600,000  (agg0b; later agg1b @R, agg2b @R+10.24MB)
  //   Wp0/1/2, eidx(1M), cursor(100K), bsums    -> end ~158.4 MB
  char* base = (char*)d_ws;
  unsigned short* xb    = (unsigned short*)base;
  unsigned short* h0b   = (unsigned short*)(base + 76800000);
  unsigned short* R     = (unsigned short*)(base + 128000000);
  unsigned short* Wp0   = (unsigned short*)(base + 153600000);
  unsigned short* Wp1   = (unsigned short*)(base + 153731072);
  unsigned short* Wp2   = (unsigned short*)(base + 153993216);
  int* eidx   = (int*)(base + 154042368);
  int* cursor = (int*)(base + 158042368);
  int* bsums  = (int*)(base + 158442368);

  unsigned short* agg0b = R;
  unsigned short* agg1b = R;
  unsigned short* agg2b = R + 5120000;  // after agg1b (20000*256)
  unsigned short* h1b   = xb;           // xb dead after gemm0

  // one-time converts/packs
  f2b_kernel<<<2048, 256, 0, stream>>>((const float4*)x, (ushort4*)xb, 9600000);
  pack_w_kernel<<<256, 256, 0, stream>>>(Ws0, Wn0, Wp0, 128, 128, 256, 256);
  pack_w_kernel<<<512, 256, 0, stream>>>(Ws1, Wn1, Wp1, 256, 256, 256, 256);
  pack_w_kernel<<<96, 256, 0, stream>>>(Ws2, Wn2, Wp2, 256, 256, 47, 48);

  // ---- layer 0: x(300000,128) -> h0(100000,256) ----
  build_csr(src0, dst0, E0, N_DST0, cursor, bsums, eidx, stream);
  gather_mean_bf16<128><<<(N_DST0 + 3) / 4, 256, 0, stream>>>(xb, cursor, eidx, agg0b, N_DST0);
  gemm_mfma<128, 128, 256, 256, true, true><<<(N_DST0 / 16 + 3) / 4, 256, 0, stream>>>(
      xb, agg0b, Wp0, b0, h0b, N_DST0);

  // ---- layer 1: h0(100000,256) -> h1(20000,256) ----
  build_csr(src1, dst1, E1, N_DST1, cursor, bsums, eidx, stream);
  gather_mean_bf16<256><<<(N_DST1 + 3) / 4, 256, 0, stream>>>(h0b, cursor, eidx, agg1b, N_DST1);
  gemm_mfma<256, 256, 256, 256, true, true><<<(N_DST1 / 16 + 3) / 4, 256, 0, stream>>>(
      h0b, agg1b, Wp1, b1, h1b, N_DST1);

  // ---- layer 2: h1(20000,256) -> out(4096,47) ----
  build_csr(src2, dst2, E2, N_DST2, cursor, bsums, eidx, stream);
  gather_mean_bf16<256><<<(N_DST2 + 3) / 4, 256, 0, stream>>>(h1b, cursor, eidx, agg2b, N_DST2);
  gemm_mfma<256, 256, 48, 47, false, false><<<(N_DST2 / 16 + 3) / 4, 256, 0, stream>>>(
      h1b, agg2b, Wp2, b2, out, N_DST2);
}

// Round 6
// 579.931 us; speedup vs baseline: 6.1463x; 1.0409x over previous
//
#include <hip/hip_runtime.h>

typedef __bf16 bf16x8 __attribute__((ext_vector_type(8)));
typedef float f32x4 __attribute__((ext_vector_type(4)));

constexpr int N_DST0 = 100000, N_DST1 = 20000, N_DST2 = 4096;
constexpr int E0 = 1000000, E1 = 300000, E2 = 61440;
constexpr int NCNT = N_DST0 + N_DST1 + N_DST2;   // 124096
constexpr int ETOT = E0 + E1 + E2;               // 1361440

// ---- bf16 helpers (RNE) ----
__device__ __forceinline__ unsigned short f2b(float f) {
  unsigned u = __builtin_bit_cast(unsigned, f);
  u += 0x7FFFu + ((u >> 16) & 1u);
  return (unsigned short)(u >> 16);
}
__device__ __forceinline__ unsigned pk2(float lo, float hi) {
  return (unsigned)f2b(lo) | ((unsigned)f2b(hi) << 16);
}
__device__ __forceinline__ float b2f_lo(unsigned u) {
  return __builtin_bit_cast(float, u << 16);
}
__device__ __forceinline__ float b2f_hi(unsigned u) {
  return __builtin_bit_cast(float, u & 0xFFFF0000u);
}

// ---------------------------------------------------------------------------
// fp32 -> bf16 bulk convert: 8 floats (32B) in, 8 bf16 (16B) out per item
// ---------------------------------------------------------------------------
__global__ __launch_bounds__(256)
void f2b_kernel(const float4* __restrict__ in, uint4* __restrict__ out, int n8) {
  int stride = gridDim.x * blockDim.x;
  for (int i = blockIdx.x * blockDim.x + threadIdx.x; i < n8; i += stride) {
    float4 a = in[2 * i], b = in[2 * i + 1];
    uint4 o;
    o.x = pk2(a.x, a.y); o.y = pk2(a.z, a.w);
    o.z = pk2(b.x, b.y); o.w = pk2(b.z, b.w);
    out[i] = o;
  }
}

// ---------------------------------------------------------------------------
// Batched weight repack (all 3 layers in one launch).
// Fragment order: out[((nt*NKT + kt)*64 + lane)*8 + j] =
//   W[kt*32 + (lane>>4)*8 + j][nt*16 + (lane&15)]  (W = [Ws;Wn], zero-pad n>=N)
// ---------------------------------------------------------------------------
__device__ __forceinline__ void pack_one(const float* __restrict__ Ws,
                                         const float* __restrict__ Wn,
                                         unsigned short* __restrict__ out,
                                         int t, int KS, int N, int NKT) {
  int j = t & 7, lane = (t >> 3) & 63;
  int kt = (t >> 9) % NKT, nt = t / (NKT << 9);
  int k = kt * 32 + (lane >> 4) * 8 + j;
  int n = nt * 16 + (lane & 15);
  float v = 0.f;
  if (n < N) v = (k < KS) ? Ws[k * N + n] : Wn[(k - KS) * N + n];
  out[t] = f2b(v);
}

__global__ __launch_bounds__(256)
void pack_w3(const float* __restrict__ Ws0, const float* __restrict__ Wn0,
             const float* __restrict__ Ws1, const float* __restrict__ Wn1,
             const float* __restrict__ Ws2, const float* __restrict__ Wn2,
             unsigned short* __restrict__ Wp0, unsigned short* __restrict__ Wp1,
             unsigned short* __restrict__ Wp2) {
  constexpr int T0 = 16 * 8 * 512;    // 65536  (NP=256, NKT=8)
  constexpr int T1 = 16 * 16 * 512;   // 131072 (NP=256, NKT=16)
  constexpr int T2 = 3 * 16 * 512;    // 24576  (NP=48,  NKT=16)
  int stride = gridDim.x * blockDim.x;
  for (int t = blockIdx.x * blockDim.x + threadIdx.x; t < T0 + T1 + T2; t += stride) {
    if (t < T0)           pack_one(Ws0, Wn0, Wp0, t, 128, 256, 8);
    else if (t < T0 + T1) pack_one(Ws1, Wn1, Wp1, t - T0, 256, 256, 16);
    else                  pack_one(Ws2, Wn2, Wp2, t - T0 - T1, 256, 47, 16);
  }
}

// ---------------------------------------------------------------------------
// Batched CSR build over all 3 graphs:
//   cnt[124096] = concat(deg0, deg1, deg2) -> exclusive scan (global) ->
//   place into one eidx[1361440]. After place, cnt[g] == global row_end(g).
// ---------------------------------------------------------------------------
__global__ void count3(const int* __restrict__ d0, const int* __restrict__ d1,
                       const int* __restrict__ d2, int* __restrict__ cnt) {
  int stride = gridDim.x * blockDim.x;
  for (int i = blockIdx.x * blockDim.x + threadIdx.x; i < ETOT; i += stride) {
    int c;
    if (i < E0) c = d0[i];
    else if (i < E0 + E1) c = N_DST0 + d1[i - E0];
    else c = N_DST0 + N_DST1 + d2[i - E0 - E1];
    atomicAdd(&cnt[c], 1);
  }
}

__global__ __launch_bounds__(256)
void scanA(int* __restrict__ io, int* __restrict__ bsums, int n) {
  __shared__ int lds[256];
  const int t = threadIdx.x;
  const int idx = blockIdx.x * 1024 + t * 4;
  int v[4];
#pragma unroll
  for (int j = 0; j < 4; ++j) v[j] = (idx + j < n) ? io[idx + j] : 0;
  int s = v[0] + v[1] + v[2] + v[3];
  lds[t] = s;
  __syncthreads();
  for (int off = 1; off < 256; off <<= 1) {
    int x = (t >= off) ? lds[t - off] : 0;
    __syncthreads();
    lds[t] += x;
    __syncthreads();
  }
  if (t == 255) bsums[blockIdx.x] = lds[255];
  int run = lds[t] - s;
#pragma unroll
  for (int j = 0; j < 4; ++j) {
    if (idx + j < n) io[idx + j] = run;
    run += v[j];
  }
}

__global__ __launch_bounds__(256)
void scanB(int* __restrict__ bsums, int nb) {
  __shared__ int lds[256];
  const int t = threadIdx.x;
  int s = (t < nb) ? bsums[t] : 0;
  lds[t] = s;
  __syncthreads();
  for (int off = 1; off < 256; off <<= 1) {
    int x = (t >= off) ? lds[t - off] : 0;
    __syncthreads();
    lds[t] += x;
    __syncthreads();
  }
  if (t < nb) bsums[t] = lds[t] - s;
}

__global__ __launch_bounds__(256)
void scanC(int* __restrict__ io, const int* __restrict__ bsums, int n) {
  const int add = bsums[blockIdx.x];
  const int idx = blockIdx.x * 1024 + threadIdx.x * 4;
#pragma unroll
  for (int j = 0; j < 4; ++j)
    if (idx + j < n) io[idx + j] += add;
}

__global__ void place3(const int* __restrict__ s0, const int* __restrict__ d0,
                       const int* __restrict__ s1, const int* __restrict__ d1,
                       const int* __restrict__ s2, const int* __restrict__ d2,
                       int* __restrict__ cursor, int* __restrict__ eidx) {
  int stride = gridDim.x * blockDim.x;
  for (int i = blockIdx.x * blockDim.x + threadIdx.x; i < ETOT; i += stride) {
    int c, sv;
    if (i < E0)           { c = d0[i];            sv = s0[i]; }
    else if (i < E0 + E1) { c = N_DST0 + d1[i - E0]; sv = s1[i - E0]; }
    else { c = N_DST0 + N_DST1 + d2[i - E0 - E1]; sv = s2[i - E0 - E1]; }
    int pos = atomicAdd(&cursor[c], 1);
    eidx[pos] = sv;
  }
}

// ---------------------------------------------------------------------------
// Gather-mean, 16B/lane loads. One wave per dst row; NSUB sub-groups of GRP
// lanes split the edge list, shfl_xor reduce across sub-groups at the end.
// GRP = D/8 (8 bf16 per 16B lane-load): D=128 -> 16 lanes, D=256 -> 32 lanes.
//   cend = cnt + layer_offset (global row_end); beg = cend[w-1] (global),
//   except global row 0. eidx positions are global.
// ---------------------------------------------------------------------------
template <int D, int FIRST>
__global__ __launch_bounds__(256)
void gather_mean(const unsigned short* __restrict__ h,
                 const int* __restrict__ cend,
                 const int* __restrict__ eidx,
                 unsigned short* __restrict__ out, int ndst) {
  constexpr int GRP = D / 8;     // lanes per row at 16B/lane  (BUGFIX: was D/16)
  constexpr int NSUB = 64 / GRP; // sub-groups per wave
  const int w = blockIdx.x * 4 + (threadIdx.x >> 6);
  if (w >= ndst) return;
  const int lane = threadIdx.x & 63;
  const int sub = lane / GRP;
  const int li = lane % GRP;
  const int beg = (FIRST && w == 0) ? 0 : cend[w - 1];
  const int end = cend[w];
  float acc[8] = {};
  const unsigned short* hp = h + li * 8;
  int e = beg + sub;
  for (; e + NSUB < end; e += 2 * NSUB) {
    uint4 u0 = *(const uint4*)(hp + (long long)eidx[e] * D);
    uint4 u1 = *(const uint4*)(hp + (long long)eidx[e + NSUB] * D);
    acc[0] += b2f_lo(u0.x); acc[1] += b2f_hi(u0.x);
    acc[2] += b2f_lo(u0.y); acc[3] += b2f_hi(u0.y);
    acc[4] += b2f_lo(u0.z); acc[5] += b2f_hi(u0.z);
    acc[6] += b2f_lo(u0.w); acc[7] += b2f_hi(u0.w);
    acc[0] += b2f_lo(u1.x); acc[1] += b2f_hi(u1.x);
    acc[2] += b2f_lo(u1.y); acc[3] += b2f_hi(u1.y);
    acc[4] += b2f_lo(u1.z); acc[5] += b2f_hi(u1.z);
    acc[6] += b2f_lo(u1.w); acc[7] += b2f_hi(u1.w);
  }
  if (e < end) {
    uint4 u = *(const uint4*)(hp + (long long)eidx[e] * D);
    acc[0] += b2f_lo(u.x); acc[1] += b2f_hi(u.x);
    acc[2] += b2f_lo(u.y); acc[3] += b2f_hi(u.y);
    acc[4] += b2f_lo(u.z); acc[5] += b2f_hi(u.z);
    acc[6] += b2f_lo(u.w); acc[7] += b2f_hi(u.w);
  }
#pragma unroll
  for (int off = GRP; off < 64; off <<= 1)
#pragma unroll
    for (int j = 0; j < 8; ++j) acc[j] += __shfl_xor(acc[j], off);
  if (sub == 0) {
    const float inv = 1.f / fmaxf((float)(end - beg), 1.f);
    uint4 o;
    o.x = pk2(acc[0] * inv, acc[1] * inv);
    o.y = pk2(acc[2] * inv, acc[3] * inv);
    o.z = pk2(acc[4] * inv, acc[5] * inv);
    o.w = pk2(acc[6] * inv, acc[7] * inv);
    *(uint4*)(out + (long long)w * D + li * 8) = o;
  }
}

// ---------------------------------------------------------------------------
// MFMA GEMM: one wave per 32-row strip-pair; A-frags in registers for whole K,
// packed W streamed (each B-frag feeds 2 strips x 2 n-tiles = 4 acc chains).
// A-frag: lane holds A[m0+s*16+(lane&15)][kt*32+(lane>>4)*8+j]
// C/D:    row = (lane>>4)*4 + reg, col = lane&15      [m89-verified]
// ---------------------------------------------------------------------------
template <int KS, int KN, int NP, int NOUT, bool RELU, bool OUT_BF16>
__global__ __launch_bounds__(256)
void gemm_mfma(const unsigned short* __restrict__ As,
               const unsigned short* __restrict__ An,
               const unsigned short* __restrict__ Wp,
               const float* __restrict__ bias, void* __restrict__ Cout, int M) {
  constexpr int NK = (KS + KN) / 32, NT = NP / 16;
  const int wave = blockIdx.x * 4 + (threadIdx.x >> 6);
  const int m0 = wave * 32;
  if (m0 >= M) return;
  const int lane = threadIdx.x & 63;
  const int g = lane >> 4, mi = lane & 15;

  bf16x8 a[2][NK];
#pragma unroll
  for (int s = 0; s < 2; ++s) {
    const long long row = m0 + s * 16 + mi;
#pragma unroll
    for (int kt = 0; kt < NK; ++kt) {
      const int k = kt * 32 + g * 8;
      const unsigned short* p = (kt * 32 < KS) ? (As + row * KS + k)
                                               : (An + row * KN + (k - KS));
      a[s][kt] = *reinterpret_cast<const bf16x8*>(p);
    }
  }
  const bf16x8* wp = reinterpret_cast<const bf16x8*>(Wp);

  auto emit = [&](int s, int nt, const f32x4& acc) {
    const int col = nt * 16 + mi;
    if (col < NOUT) {
      const float bv = bias[col];
#pragma unroll
      for (int j = 0; j < 4; ++j) {
        const long long r = m0 + s * 16 + g * 4 + j;
        float v = acc[j] + bv;
        if (RELU) v = fmaxf(v, 0.f);
        if (OUT_BF16) ((unsigned short*)Cout)[r * NOUT + col] = f2b(v);
        else          ((float*)Cout)[r * NOUT + col] = v;
      }
    }
  };

#pragma unroll 1
  for (int nt = 0; nt + 2 <= NT; nt += 2) {
    f32x4 a00 = {0.f,0.f,0.f,0.f}, a01 = {0.f,0.f,0.f,0.f};
    f32x4 a10 = {0.f,0.f,0.f,0.f}, a11 = {0.f,0.f,0.f,0.f};
#pragma unroll
    for (int kt = 0; kt < NK; ++kt) {
      bf16x8 b0 = wp[(nt * NK + kt) * 64 + lane];
      bf16x8 b1 = wp[((nt + 1) * NK + kt) * 64 + lane];
      a00 = __builtin_amdgcn_mfma_f32_16x16x32_bf16(a[0][kt], b0, a00, 0, 0, 0);
      a10 = __builtin_amdgcn_mfma_f32_16x16x32_bf16(a[1][kt], b0, a10, 0, 0, 0);
      a01 = __builtin_amdgcn_mfma_f32_16x16x32_bf16(a[0][kt], b1, a01, 0, 0, 0);
      a11 = __builtin_amdgcn_mfma_f32_16x16x32_bf16(a[1][kt], b1, a11, 0, 0, 0);
    }
    emit(0, nt, a00); emit(0, nt + 1, a01);
    emit(1, nt, a10); emit(1, nt + 1, a11);
  }
  if (NT & 1) {
    f32x4 a0 = {0.f,0.f,0.f,0.f}, a1 = {0.f,0.f,0.f,0.f};
#pragma unroll
    for (int kt = 0; kt < NK; ++kt) {
      bf16x8 b = wp[((NT - 1) * NK + kt) * 64 + lane];
      a0 = __builtin_amdgcn_mfma_f32_16x16x32_bf16(a[0][kt], b, a0, 0, 0, 0);
      a1 = __builtin_amdgcn_mfma_f32_16x16x32_bf16(a[1][kt], b, a1, 0, 0, 0);
    }
    emit(0, NT - 1, a0);
    emit(1, NT - 1, a1);
  }
}

extern "C" void kernel_launch(void* const* d_in, const int* in_sizes, int n_in,
                              void* d_out, int out_size, void* d_ws, size_t ws_size,
                              hipStream_t stream) {
  const float* x   = (const float*)d_in[0];
  const int* src0  = (const int*)d_in[1];
  const int* dst0  = (const int*)d_in[2];
  const int* src1  = (const int*)d_in[3];
  const int* dst1  = (const int*)d_in[4];
  const int* src2  = (const int*)d_in[5];
  const int* dst2  = (const int*)d_in[6];
  const float* Ws0 = (const float*)d_in[7];
  const float* Wn0 = (const float*)d_in[8];
  const float* b0  = (const float*)d_in[9];
  const float* Ws1 = (const float*)d_in[10];
  const float* Wn1 = (const float*)d_in[11];
  const float* b1  = (const float*)d_in[12];
  const float* Ws2 = (const float*)d_in[13];
  const float* Wn2 = (const float*)d_in[14];
  const float* b2  = (const float*)d_in[15];
  float* out = (float*)d_out;

  char* base = (char*)d_ws;
  unsigned short* xb  = (unsigned short*)base;                  // 76.8 MB
  unsigned short* h0b = (unsigned short*)(base + 76800000);     // 51.2 MB
  unsigned short* R   = (unsigned short*)(base + 128000000);    // 25.6 MB
  unsigned short* Wp0 = (unsigned short*)(base + 153600000);    // 131072 B
  unsigned short* Wp1 = (unsigned short*)(base + 153731072);    // 262144 B
  unsigned short* Wp2 = (unsigned short*)(base + 153993216);    //  49152 B
  int* eidx = (int*)(base + 154042368);                         // 5,445,760 B
  int* cnt  = (int*)(base + 159488128);                         //   496,384 B
  int* bsums = (int*)(base + 159985664);

  unsigned short* agg0b = R;
  unsigned short* agg1b = R;
  unsigned short* agg2b = R + 5120000;
  unsigned short* h1b   = xb;  // xb dead after gemm0

  // ---- prep: convert x, pack all weights, build all 3 CSRs ----
  f2b_kernel<<<2048, 256, 0, stream>>>((const float4*)x, (uint4*)xb, 4800000);
  pack_w3<<<432, 256, 0, stream>>>(Ws0, Wn0, Ws1, Wn1, Ws2, Wn2, Wp0, Wp1, Wp2);
  hipMemsetAsync(cnt, 0, (size_t)NCNT * 4, stream);
  count3<<<2048, 256, 0, stream>>>(dst0, dst1, dst2, cnt);
  const int nb = (NCNT + 1023) / 1024;  // 122
  scanA<<<nb, 256, 0, stream>>>(cnt, bsums, NCNT);
  scanB<<<1, 256, 0, stream>>>(bsums, nb);
  scanC<<<nb, 256, 0, stream>>>(cnt, bsums, NCNT);
  place3<<<2048, 256, 0, stream>>>(src0, dst0, src1, dst1, src2, dst2, cnt, eidx);

  // ---- layer 0: x(300000,128) -> h0(100000,256) ----
  gather_mean<128, 1><<<(N_DST0 + 3) / 4, 256, 0, stream>>>(xb, cnt, eidx, agg0b, N_DST0);
  gemm_mfma<128, 128, 256, 256, true, true><<<(N_DST0 / 32 + 3) / 4, 256, 0, stream>>>(
      xb, agg0b, Wp0, b0, h0b, N_DST0);

  // ---- layer 1: h0(100000,256) -> h1(20000,256) ----
  gather_mean<256, 0><<<(N_DST1 + 3) / 4, 256, 0, stream>>>(h0b, cnt + N_DST0, eidx, agg1b, N_DST1);
  gemm_mfma<256, 256, 256, 256, true, true><<<(N_DST1 / 32 + 3) / 4, 256, 0, stream>>>(
      h0b, agg1b, Wp1, b1, h1b, N_DST1);

  // ---- layer 2: h1(20000,256) -> out(4096,47) ----
  gather_mean<256, 0><<<(N_DST2 + 3) / 4, 256, 0, stream>>>(h1b, cnt + N_DST0 + N_DST1, eidx, agg2b, N_DST2);
  gemm_mfma<256, 256, 48, 47, false, false><<<(N_DST2 / 32 + 3) / 4, 256, 0, stream>>>(
      h1b, agg2b, Wp2, b2, out, N_DST2);
}

// Round 7
// 475.781 us; speedup vs baseline: 7.4917x; 1.2189x over previous
//
#include <hip/hip_runtime.h>

typedef __bf16 bf16x8 __attribute__((ext_vector_type(8)));
typedef float f32x4 __attribute__((ext_vector_type(4)));

constexpr int N_DST0 = 100000, N_DST1 = 20000, N_DST2 = 4096;
constexpr int E0 = 1000000, E1 = 300000, E2 = 61440;
constexpr int NCNT = N_DST0 + N_DST1 + N_DST2;   // 124096
constexpr int ETOT = E0 + E1 + E2;               // 1361440

constexpr int BKT = 256;       // buckets (g>>9); used: 0..242
constexpr int NBKT_USED = (NCNT + 511) / 512;    // 243
constexpr int CAP = 16384;     // per-bucket pair capacity (2x expected max)
constexpr int TILE_A = 4096;   // edges per binA block
constexpr int NB_A = (ETOT + TILE_A - 1) / TILE_A;  // 333

// ---- bf16 helpers (RNE) ----
__device__ __forceinline__ unsigned short f2b(float f) {
  unsigned u = __builtin_bit_cast(unsigned, f);
  u += 0x7FFFu + ((u >> 16) & 1u);
  return (unsigned short)(u >> 16);
}
__device__ __forceinline__ unsigned pk2(float lo, float hi) {
  return (unsigned)f2b(lo) | ((unsigned)f2b(hi) << 16);
}
__device__ __forceinline__ float b2f_lo(unsigned u) {
  return __builtin_bit_cast(float, u << 16);
}
__device__ __forceinline__ float b2f_hi(unsigned u) {
  return __builtin_bit_cast(float, u & 0xFFFF0000u);
}

// ---------------------------------------------------------------------------
// fp32 -> bf16 bulk convert: 8 floats in, 8 bf16 out per item
// ---------------------------------------------------------------------------
__global__ __launch_bounds__(256)
void f2b_kernel(const float4* __restrict__ in, uint4* __restrict__ out, int n8) {
  int stride = gridDim.x * blockDim.x;
  for (int i = blockIdx.x * blockDim.x + threadIdx.x; i < n8; i += stride) {
    float4 a = in[2 * i], b = in[2 * i + 1];
    uint4 o;
    o.x = pk2(a.x, a.y); o.y = pk2(a.z, a.w);
    o.z = pk2(b.x, b.y); o.w = pk2(b.z, b.w);
    out[i] = o;
  }
}

// ---------------------------------------------------------------------------
// Batched weight repack (all 3 layers, one launch). Fragment order:
// out[((nt*NKT + kt)*64 + lane)*8 + j] = W[kt*32+(lane>>4)*8+j][nt*16+(lane&15)]
// ---------------------------------------------------------------------------
__device__ __forceinline__ void pack_one(const float* __restrict__ Ws,
                                         const float* __restrict__ Wn,
                                         unsigned short* __restrict__ out,
                                         int t, int KS, int N, int NKT) {
  int j = t & 7, lane = (t >> 3) & 63;
  int kt = (t >> 9) % NKT, nt = t / (NKT << 9);
  int k = kt * 32 + (lane >> 4) * 8 + j;
  int n = nt * 16 + (lane & 15);
  float v = 0.f;
  if (n < N) v = (k < KS) ? Ws[k * N + n] : Wn[(k - KS) * N + n];
  out[t] = f2b(v);
}

__global__ __launch_bounds__(256)
void pack_w3(const float* __restrict__ Ws0, const float* __restrict__ Wn0,
             const float* __restrict__ Ws1, const float* __restrict__ Wn1,
             const float* __restrict__ Ws2, const float* __restrict__ Wn2,
             unsigned short* __restrict__ Wp0, unsigned short* __restrict__ Wp1,
             unsigned short* __restrict__ Wp2) {
  constexpr int T0 = 16 * 8 * 512;
  constexpr int T1 = 16 * 16 * 512;
  constexpr int T2 = 3 * 16 * 512;
  int stride = gridDim.x * blockDim.x;
  for (int t = blockIdx.x * blockDim.x + threadIdx.x; t < T0 + T1 + T2; t += stride) {
    if (t < T0)           pack_one(Ws0, Wn0, Wp0, t, 128, 256, 8);
    else if (t < T0 + T1) pack_one(Ws1, Wn1, Wp1, t - T0, 256, 256, 16);
    else                  pack_one(Ws2, Wn2, Wp2, t - T0 - T1, 256, 47, 16);
  }
}

// ---------------------------------------------------------------------------
// Binned CSR build, pass A: per-block LDS bucket histogram + rank capture,
// one global atomic per (block,bucket) chunk reservation, pair scatter into
// per-bucket fixed-CAP regions. Pair = (src, g).
// ---------------------------------------------------------------------------
__device__ __forceinline__ void edge_at(int i,
    const int* __restrict__ s0, const int* __restrict__ d0,
    const int* __restrict__ s1, const int* __restrict__ d1,
    const int* __restrict__ s2, const int* __restrict__ d2,
    int& s, int& g) {
  if (i < E0)           { g = d0[i];                     s = s0[i]; }
  else if (i < E0 + E1) { g = N_DST0 + d1[i - E0];       s = s1[i - E0]; }
  else                  { g = N_DST0 + N_DST1 + d2[i - E0 - E1]; s = s2[i - E0 - E1]; }
}

__global__ __launch_bounds__(256)
void binA(const int* __restrict__ s0, const int* __restrict__ d0,
          const int* __restrict__ s1, const int* __restrict__ d1,
          const int* __restrict__ s2, const int* __restrict__ d2,
          int* __restrict__ gcnt, uint2* __restrict__ pairs) {
  __shared__ int lhist[BKT];
  __shared__ int lbase[BKT];
  const int t = threadIdx.x;
  lhist[t] = 0;
  __syncthreads();
  const int base = blockIdx.x * TILE_A;
  int r[16];
#pragma unroll
  for (int j = 0; j < 16; ++j) {
    int i = base + j * 256 + t;
    r[j] = -1;
    if (i < ETOT) {
      int s, g;
      edge_at(i, s0, d0, s1, d1, s2, d2, s, g);
      r[j] = atomicAdd(&lhist[g >> 9], 1);
    }
  }
  __syncthreads();
  {
    int n = lhist[t];
    lbase[t] = (n > 0) ? atomicAdd(&gcnt[t], n) : 0;
  }
  __syncthreads();
#pragma unroll
  for (int j = 0; j < 16; ++j) {
    int i = base + j * 256 + t;
    if (i < ETOT) {
      int s, g;
      edge_at(i, s0, d0, s1, d1, s2, d2, s, g);
      int b = g >> 9;
      int rel = lbase[b] + r[j];
      if (rel < CAP)
        pairs[(long long)b * CAP + rel] = make_uint2((unsigned)s, (unsigned)g);
    }
  }
}

// exclusive scan of gcnt[256] -> bbase[256]
__global__ __launch_bounds__(256)
void scan256(const int* __restrict__ gcnt, int* __restrict__ bbase) {
  __shared__ int lds[256];
  const int t = threadIdx.x;
  int v = gcnt[t];
  lds[t] = v;
  __syncthreads();
  for (int off = 1; off < 256; off <<= 1) {
    int x = (t >= off) ? lds[t - off] : 0;
    __syncthreads();
    lds[t] += x;
    __syncthreads();
  }
  bbase[t] = lds[t] - v;
}

// ---------------------------------------------------------------------------
// Pass B: one block per bucket. LDS 512-row histogram -> LDS scan ->
// global row_end (coalesced) -> place eidx via LDS cursors.
// ---------------------------------------------------------------------------
__global__ __launch_bounds__(256)
void binB(const uint2* __restrict__ pairs, const int* __restrict__ gcnt,
          const int* __restrict__ bbase, int* __restrict__ eidx,
          int* __restrict__ row_end) {
  __shared__ int hist[512];
  __shared__ int excl[512];
  __shared__ int cur[512];
  const int b = blockIdx.x;
  const int t = threadIdx.x;
  const int n = min(gcnt[b], CAP);
  const int gb = bbase[b];
  hist[t] = 0; hist[t + 256] = 0;
  __syncthreads();
  const uint2* pb = pairs + (long long)b * CAP;
  for (int i = t; i < n; i += 256)
    atomicAdd(&hist[pb[i].y & 511], 1);
  __syncthreads();
  // exclusive scan of hist[512] with 256 threads (2 elems/thread)
  int h0 = hist[2 * t], h1 = hist[2 * t + 1];
  int s = h0 + h1;
  cur[t] = s;
  __syncthreads();
  for (int off = 1; off < 256; off <<= 1) {
    int x = (t >= off) ? cur[t - off] : 0;
    __syncthreads();
    cur[t] += x;
    __syncthreads();
  }
  int ex = cur[t] - s;
  excl[2 * t] = ex;
  excl[2 * t + 1] = ex + h0;
  __syncthreads();
  cur[t] = excl[t];
  cur[t + 256] = excl[t + 256];
  const int g0 = (b << 9) + t, g1 = (b << 9) + t + 256;
  if (g0 < NCNT) row_end[g0] = gb + excl[t] + hist[t];
  if (g1 < NCNT) row_end[g1] = gb + excl[t + 256] + hist[t + 256];
  __syncthreads();
  for (int i = t; i < n; i += 256) {
    uint2 p = pb[i];
    int pos = gb + atomicAdd(&cur[p.y & 511], 1);
    eidx[pos] = (int)p.x;
  }
}

// ---------------------------------------------------------------------------
// Gather-mean, 16B/lane. GRP = D/8 lanes per row; NSUB sub-groups split the
// edge list; shfl_xor reduce. cend = row_end + layer offset (global ranges).
// ---------------------------------------------------------------------------
template <int D, int FIRST>
__global__ __launch_bounds__(256)
void gather_mean(const unsigned short* __restrict__ h,
                 const int* __restrict__ cend,
                 const int* __restrict__ eidx,
                 unsigned short* __restrict__ out, int ndst) {
  constexpr int GRP = D / 8;
  constexpr int NSUB = 64 / GRP;
  const int w = blockIdx.x * 4 + (threadIdx.x >> 6);
  if (w >= ndst) return;
  const int lane = threadIdx.x & 63;
  const int sub = lane / GRP;
  const int li = lane % GRP;
  const int beg = (FIRST && w == 0) ? 0 : cend[w - 1];
  const int end = cend[w];
  float acc[8] = {};
  const unsigned short* hp = h + li * 8;
  int e = beg + sub;
  for (; e + NSUB < end; e += 2 * NSUB) {
    uint4 u0 = *(const uint4*)(hp + (long long)eidx[e] * D);
    uint4 u1 = *(const uint4*)(hp + (long long)eidx[e + NSUB] * D);
    acc[0] += b2f_lo(u0.x); acc[1] += b2f_hi(u0.x);
    acc[2] += b2f_lo(u0.y); acc[3] += b2f_hi(u0.y);
    acc[4] += b2f_lo(u0.z); acc[5] += b2f_hi(u0.z);
    acc[6] += b2f_lo(u0.w); acc[7] += b2f_hi(u0.w);
    acc[0] += b2f_lo(u1.x); acc[1] += b2f_hi(u1.x);
    acc[2] += b2f_lo(u1.y); acc[3] += b2f_hi(u1.y);
    acc[4] += b2f_lo(u1.z); acc[5] += b2f_hi(u1.z);
    acc[6] += b2f_lo(u1.w); acc[7] += b2f_hi(u1.w);
  }
  if (e < end) {
    uint4 u = *(const uint4*)(hp + (long long)eidx[e] * D);
    acc[0] += b2f_lo(u.x); acc[1] += b2f_hi(u.x);
    acc[2] += b2f_lo(u.y); acc[3] += b2f_hi(u.y);
    acc[4] += b2f_lo(u.z); acc[5] += b2f_hi(u.z);
    acc[6] += b2f_lo(u.w); acc[7] += b2f_hi(u.w);
  }
#pragma unroll
  for (int off = GRP; off < 64; off <<= 1)
#pragma unroll
    for (int j = 0; j < 8; ++j) acc[j] += __shfl_xor(acc[j], off);
  if (sub == 0) {
    const float inv = 1.f / fmaxf((float)(end - beg), 1.f);
    uint4 o;
    o.x = pk2(acc[0] * inv, acc[1] * inv);
    o.y = pk2(acc[2] * inv, acc[3] * inv);
    o.z = pk2(acc[4] * inv, acc[5] * inv);
    o.w = pk2(acc[6] * inv, acc[7] * inv);
    *(uint4*)(out + (long long)w * D + li * 8) = o;
  }
}

// ---------------------------------------------------------------------------
// MFMA GEMM: one wave per 32-row strip-pair; A-frags in registers for whole K,
// packed W streamed (each B-frag feeds 2 strips x 2 n-tiles = 4 acc chains).
// ---------------------------------------------------------------------------
template <int KS, int KN, int NP, int NOUT, bool RELU, bool OUT_BF16>
__global__ __launch_bounds__(256)
void gemm_mfma(const unsigned short* __restrict__ As,
               const unsigned short* __restrict__ An,
               const unsigned short* __restrict__ Wp,
               const float* __restrict__ bias, void* __restrict__ Cout, int M) {
  constexpr int NK = (KS + KN) / 32, NT = NP / 16;
  const int wave = blockIdx.x * 4 + (threadIdx.x >> 6);
  const int m0 = wave * 32;
  if (m0 >= M) return;
  const int lane = threadIdx.x & 63;
  const int g = lane >> 4, mi = lane & 15;

  bf16x8 a[2][NK];
#pragma unroll
  for (int s = 0; s < 2; ++s) {
    const long long row = m0 + s * 16 + mi;
#pragma unroll
    for (int kt = 0; kt < NK; ++kt) {
      const int k = kt * 32 + g * 8;
      const unsigned short* p = (kt * 32 < KS) ? (As + row * KS + k)
                                               : (An + row * KN + (k - KS));
      a[s][kt] = *reinterpret_cast<const bf16x8*>(p);
    }
  }
  const bf16x8* wp = reinterpret_cast<const bf16x8*>(Wp);

  auto emit = [&](int s, int nt, const f32x4& acc) {
    const int col = nt * 16 + mi;
    if (col < NOUT) {
      const float bv = bias[col];
#pragma unroll
      for (int j = 0; j < 4; ++j) {
        const long long r = m0 + s * 16 + g * 4 + j;
        float v = acc[j] + bv;
        if (RELU) v = fmaxf(v, 0.f);
        if (OUT_BF16) ((unsigned short*)Cout)[r * NOUT + col] = f2b(v);
        else          ((float*)Cout)[r * NOUT + col] = v;
      }
    }
  };

#pragma unroll 1
  for (int nt = 0; nt + 2 <= NT; nt += 2) {
    f32x4 a00 = {0.f,0.f,0.f,0.f}, a01 = {0.f,0.f,0.f,0.f};
    f32x4 a10 = {0.f,0.f,0.f,0.f}, a11 = {0.f,0.f,0.f,0.f};
#pragma unroll
    for (int kt = 0; kt < NK; ++kt) {
      bf16x8 b0 = wp[(nt * NK + kt) * 64 + lane];
      bf16x8 b1 = wp[((nt + 1) * NK + kt) * 64 + lane];
      a00 = __builtin_amdgcn_mfma_f32_16x16x32_bf16(a[0][kt], b0, a00, 0, 0, 0);
      a10 = __builtin_amdgcn_mfma_f32_16x16x32_bf16(a[1][kt], b0, a10, 0, 0, 0);
      a01 = __builtin_amdgcn_mfma_f32_16x16x32_bf16(a[0][kt], b1, a01, 0, 0, 0);
      a11 = __builtin_amdgcn_mfma_f32_16x16x32_bf16(a[1][kt], b1, a11, 0, 0, 0);
    }
    emit(0, nt, a00); emit(0, nt + 1, a01);
    emit(1, nt, a10); emit(1, nt + 1, a11);
  }
  if (NT & 1) {
    f32x4 a0 = {0.f,0.f,0.f,0.f}, a1 = {0.f,0.f,0.f,0.f};
#pragma unroll
    for (int kt = 0; kt < NK; ++kt) {
      bf16x8 b = wp[((NT - 1) * NK + kt) * 64 + lane];
      a0 = __builtin_amdgcn_mfma_f32_16x16x32_bf16(a[0][kt], b, a0, 0, 0, 0);
      a1 = __builtin_amdgcn_mfma_f32_16x16x32_bf16(a[1][kt], b, a1, 0, 0, 0);
    }
    emit(0, NT - 1, a0);
    emit(1, NT - 1, a1);
  }
}

extern "C" void kernel_launch(void* const* d_in, const int* in_sizes, int n_in,
                              void* d_out, int out_size, void* d_ws, size_t ws_size,
                              hipStream_t stream) {
  const float* x   = (const float*)d_in[0];
  const int* src0  = (const int*)d_in[1];
  const int* dst0  = (const int*)d_in[2];
  const int* src1  = (const int*)d_in[3];
  const int* dst1  = (const int*)d_in[4];
  const int* src2  = (const int*)d_in[5];
  const int* dst2  = (const int*)d_in[6];
  const float* Ws0 = (const float*)d_in[7];
  const float* Wn0 = (const float*)d_in[8];
  const float* b0  = (const float*)d_in[9];
  const float* Ws1 = (const float*)d_in[10];
  const float* Wn1 = (const float*)d_in[11];
  const float* b1  = (const float*)d_in[12];
  const float* Ws2 = (const float*)d_in[13];
  const float* Wn2 = (const float*)d_in[14];
  const float* b2  = (const float*)d_in[15];
  float* out = (float*)d_out;

  char* base = (char*)d_ws;
  unsigned short* xb  = (unsigned short*)base;                  // 76.8 MB
  unsigned short* h0b = (unsigned short*)(base + 76800000);     // 51.2 MB
  unsigned short* R   = (unsigned short*)(base + 128000000);    // 25.6 MB
  unsigned short* Wp0 = (unsigned short*)(base + 153600000);
  unsigned short* Wp1 = (unsigned short*)(base + 153731072);
  unsigned short* Wp2 = (unsigned short*)(base + 153993216);
  int* eidx  = (int*)(base + 154042368);                        // 5,445,760 B
  int* cnt   = (int*)(base + 159488128);                        // row_end, 496,384 B
  int* gcnt  = (int*)(base + 159985664);                        // 1 KB
  int* bbase = (int*)(base + 159986688);                        // 1 KB

  // pairs buffer (33.6 MB) overlays h0b region: consumed by binB before
  // gather0/gemm0 produce agg0b/h0b.
  uint2* pairs = (uint2*)(base + 76800000);

  unsigned short* agg0b = R;
  unsigned short* agg1b = R;
  unsigned short* agg2b = R + 5120000;
  unsigned short* h1b   = xb;  // xb dead after gemm0

  // ---- prep: convert x, pack weights, binned CSR build ----
  f2b_kernel<<<2048, 256, 0, stream>>>((const float4*)x, (uint4*)xb, 4800000);
  pack_w3<<<432, 256, 0, stream>>>(Ws0, Wn0, Ws1, Wn1, Ws2, Wn2, Wp0, Wp1, Wp2);
  hipMemsetAsync(gcnt, 0, BKT * 4, stream);
  binA<<<NB_A, 256, 0, stream>>>(src0, dst0, src1, dst1, src2, dst2, gcnt, pairs);
  scan256<<<1, 256, 0, stream>>>(gcnt, bbase);
  binB<<<NBKT_USED, 256, 0, stream>>>(pairs, gcnt, bbase, eidx, cnt);

  // ---- layer 0: x(300000,128) -> h0(100000,256) ----
  gather_mean<128, 1><<<(N_DST0 + 3) / 4, 256, 0, stream>>>(xb, cnt, eidx, agg0b, N_DST0);
  gemm_mfma<128, 128, 256, 256, true, true><<<(N_DST0 / 32 + 3) / 4, 256, 0, stream>>>(
      xb, agg0b, Wp0, b0, h0b, N_DST0);

  // ---- layer 1: h0(100000,256) -> h1(20000,256) ----
  gather_mean<256, 0><<<(N_DST1 + 3) / 4, 256, 0, stream>>>(h0b, cnt + N_DST0, eidx, agg1b, N_DST1);
  gemm_mfma<256, 256, 256, 256, true, true><<<(N_DST1 / 32 + 3) / 4, 256, 0, stream>>>(
      h0b, agg1b, Wp1, b1, h1b, N_DST1);

  // ---- layer 2: h1(20000,256) -> out(4096,47) ----
  gather_mean<256, 0><<<(N_DST2 + 3) / 4, 256, 0, stream>>>(h1b, cnt + N_DST0 + N_DST1, eidx, agg2b, N_DST2);
  gemm_mfma<256, 256, 48, 47, false, false><<<(N_DST2 / 32 + 3) / 4, 256, 0, stream>>>(
      h1b, agg2b, Wp2, b2, out, N_DST2);
}